// Round 3
// baseline (280.770 us; speedup 1.0000x reference)
//
#include <hip/hip_runtime.h>
#include <math.h>

#define T_ 256
#define B_ 128
#define D_ 1024
#define K_ 21
#define NB3 43  // ceil(B_/3) wave-blocks for each scan flavor

typedef short v8s __attribute__((ext_vector_type(8)));
typedef float v4f __attribute__((ext_vector_type(4)));

__device__ __forceinline__ short bf16rne(float f) {
  unsigned u = __float_as_uint(f);
  u += 0x7FFFu + ((u >> 16) & 1u);  // round-nearest-even
  return (short)(u >> 16);
}
__device__ __forceinline__ float rdl(float v, int l) {
  return __int_as_float(__builtin_amdgcn_readlane(__float_as_int(v), l));
}
__device__ __forceinline__ int imax3(int a, int b, int c) {
  const int t = a > b ? a : b;  // fuses to v_max3_i32
  return t > c ? t : c;
}

typedef const __attribute__((address_space(1))) void* gas1_t;
typedef __attribute__((address_space(3))) void* las3_t;
// wave-wide async global->LDS: lane i's dword lands at lptr + 4*i
__device__ __forceinline__ void gload_lds(const float* g, float* l) {
  __builtin_amdgcn_global_load_lds((gas1_t)g, (las3_t)l, 4, 0, 0);
}

// ---------------------------------------------------------------------------
// Kernel 1: FC as bf16 MFMA GEMM. Block = 256 thr (4 waves); wave wv owns
// k-chunk [wv*256, +256) for rows [blockIdx.x*64, +64). Also zeroes out_loss
// (block 0) so no separate memset dispatch is needed.
// ---------------------------------------------------------------------------
__global__ __launch_bounds__(256) void fc_kernel(
    const float* __restrict__ A, const float* __restrict__ W,
    const float* __restrict__ bias, float* __restrict__ fc,
    float* __restrict__ out_loss) {
  __shared__ float red[3][64][22];
  if (blockIdx.x == 0 && threadIdx.x == 0) *out_loss = 0.f;
  const int lane = threadIdx.x & 63;
  const int wv = threadIdx.x >> 6;
  const int m15 = lane & 15, g4 = lane >> 4;
  const int rowbase = blockIdx.x * 64;
  const int kc = wv * 256;
  const int n1 = 16 + m15;

  v8s bf[8][2];
#pragma unroll
  for (int s = 0; s < 8; ++s) {
    const float* Wp = W + (size_t)(kc + 32 * s + 8 * g4) * K_;
#pragma unroll
    for (int j = 0; j < 8; ++j) bf[s][0][j] = bf16rne(Wp[j * K_ + m15]);
    if (n1 < K_) {
#pragma unroll
      for (int j = 0; j < 8; ++j) bf[s][1][j] = bf16rne(Wp[j * K_ + n1]);
    } else {
#pragma unroll
      for (int j = 0; j < 8; ++j) bf[s][1][j] = 0;
    }
  }

  v4f acc[4][2];
#pragma unroll
  for (int m = 0; m < 4; ++m) {
    acc[m][0] = (v4f)(0.f);
    acc[m][1] = (v4f)(0.f);
  }

#pragma unroll
  for (int s = 0; s < 8; ++s) {
    v8s av[4];
#pragma unroll
    for (int m = 0; m < 4; ++m) {
      const float* Ap =
          A + (size_t)(rowbase + 16 * m + m15) * D_ + kc + 32 * s + 8 * g4;
      const float4 x = *(const float4*)Ap;
      const float4 y = *(const float4*)(Ap + 4);
      av[m][0] = bf16rne(x.x); av[m][1] = bf16rne(x.y);
      av[m][2] = bf16rne(x.z); av[m][3] = bf16rne(x.w);
      av[m][4] = bf16rne(y.x); av[m][5] = bf16rne(y.y);
      av[m][6] = bf16rne(y.z); av[m][7] = bf16rne(y.w);
    }
#pragma unroll
    for (int m = 0; m < 4; ++m) {
      acc[m][0] = __builtin_amdgcn_mfma_f32_16x16x32_bf16(av[m], bf[s][0],
                                                          acc[m][0], 0, 0, 0);
      acc[m][1] = __builtin_amdgcn_mfma_f32_16x16x32_bf16(av[m], bf[s][1],
                                                          acc[m][1], 0, 0, 0);
    }
  }

  if (wv > 0) {
#pragma unroll
    for (int m = 0; m < 4; ++m)
#pragma unroll
      for (int ri = 0; ri < 4; ++ri) {
        const int rl = 16 * m + 4 * g4 + ri;
        red[wv - 1][rl][m15] = acc[m][0][ri];
        if (n1 < K_) red[wv - 1][rl][n1] = acc[m][1][ri];
      }
  }
  __syncthreads();
  if (wv == 0) {
    const float b0 = bias[m15];
    const float b1 = (n1 < K_) ? bias[n1] : 0.f;
#pragma unroll
    for (int m = 0; m < 4; ++m)
#pragma unroll
      for (int ri = 0; ri < 4; ++ri) {
        const int rl = 16 * m + 4 * g4 + ri;
        float* o = fc + (size_t)(rowbase + rl) * K_;
        o[m15] = acc[m][0][ri] + red[0][rl][m15] + red[1][rl][m15] +
                 red[2][rl][m15] + b0;
        if (n1 < K_)
          o[n1] = acc[m][1][ri] + red[0][rl][n1] + red[1][rl][n1] +
                  red[2][rl][n1] + b1;
      }
  }
}

// ---------------------------------------------------------------------------
// Kernel 2: sequential scans. 3 batches per wave, lane = g*21 + jloc.
// v2: per-step all-gather through an LDS state vector (1 ds_write_b32 +
//     5 ds_read_b128 + 1 ds_read_b32, per-wave in-order => no barrier).
// v4: fc staged into LDS in 32-step chunks via global_load_lds (double
//     buffered, 16 KB). The 3 batches are contiguous (63 floats/row), so
//     one wave-wide dword load stages a whole t-row. The in-loop fc access
//     is a conflict-free ds_read_b32 issued first in the step (in-order DS
//     pipe returns it before the state reads). One vmcnt(0) per 32 steps,
//     issued a full chunk (~5000 cy) after the loads => free. Viterbi max
//     tree uses v_max3_i32 triples; bp store is unguarded (lane 63 is a
//     bit-identical duplicate of lane 62).
// Blocks [0,43): forward; [43,86): Viterbi; [86,214): numerator.
// ---------------------------------------------------------------------------
__global__ __launch_bounds__(64) void scan_kernel(
    const float* __restrict__ fc, const int* __restrict__ tags,
    const float* __restrict__ startT, const float* __restrict__ endT,
    const float* __restrict__ trans, float* __restrict__ out_tags,
    float* __restrict__ out_loss) {
  __shared__ v4f statev[18];               // 3 groups x 24 floats (21 + pad)
  __shared__ float fcs[2][32][64];         // fc chunk double-buffer, 16 KB
  __shared__ unsigned short bp[256 * 66];  // bp[t][g][tag], stride 66/22
  __shared__ unsigned char h2[127 * 66];   // tag@2v   <- tag@(2v+2)
  __shared__ unsigned char h4[63 * 66];    // tag@4w   <- tag@(4w+4)
  __shared__ unsigned char cur[3 * 256];

  const int lane = threadIdx.x;
  const int blk = blockIdx.x;

  if (blk < 2 * NB3) {
    const bool fwd = blk < NB3;
    const int bblk = fwd ? blk : blk - NB3;
    int g = lane / 21;
    if (g > 2) g = 2;
    int jloc = lane - g * 21;
    if (jloc > 20) jloc = 20;
    const int gj = g * 21 + jloc;  // = lane for lane<63; 62 for lane 63
    const int b0 = bblk * 3;

    // lengths per group (uniform, via ballots); mask[t] == (t < len)
    int len0 = 0, len1 = 0, len2 = 0;
#pragma unroll
    for (int q = 0; q < 4; ++q) {
      const int t = q * 64 + lane;
      int bb0 = b0, bb1 = b0 + 1, bb2 = b0 + 2;
      if (bb1 >= B_) bb1 = B_ - 1;
      if (bb2 >= B_) bb2 = B_ - 1;
      len0 += __popcll(__ballot(tags[t * B_ + bb0] != 0));
      len1 += __popcll(__ballot(tags[t * B_ + bb1] != 0));
      len2 += __popcll(__ballot(tags[t * B_ + bb2] != 0));
    }
    const int mylen = (g == 0) ? len0 : (g == 1) ? len1 : len2;

    float* sb = (float*)statev + g * 24;   // this group's state (21 floats)
    const v4f* sv = (const v4f*)sb;        // 16B-aligned (24 floats = 96B)

    // ---- fc chunk staging: rows t = 32c..32c+31 -> fcs[c&1][t&31][lane]
#define STAGE(c)                                                             \
    {                                                                        \
      const float* src_ = fc + ((size_t)((c) * 32) * B_ + b0) * K_ + lane;   \
      float* dst_ = &fcs[(c) & 1][0][0];                                     \
      _Pragma("unroll")                                                      \
      for (int q_ = 0; q_ < 32; ++q_)                                        \
        gload_lds(src_ + (size_t)q_ * (B_ * K_), dst_ + q_ * 64);            \
    }
#define WAIT_VM0()                                                           \
    {                                                                        \
      asm volatile("s_waitcnt vmcnt(0)" ::: "memory");                       \
      __builtin_amdgcn_sched_barrier(0);                                     \
    }

    STAGE(0)
    WAIT_VM0()
    const float em0 = fcs[0][0][gj];
    STAGE(1)

    if (fwd) {
      // ---------------- forward / denominator (linear domain) ------------
      float ec[21];  // exp(trans[:, jloc]) straight (no rotation)
#pragma unroll
      for (int i = 0; i < K_; ++i) ec[i] = __expf(trans[i * K_ + jloc]);
      float p = __expf(startT[jloc] + em0);
      sb[jloc] = p;  // lane 63 duplicates lane 62's write (same value)
      float L = 0.f;

      for (int c = 0; c < 8; ++c) {
        const float* fb = &fcs[c & 1][0][0];
        const int t1 = c * 32 + 32;
        for (int t = c ? c * 32 : 1; t < t1; ++t) {
          // fc read issued first: in-order DS pipe returns it before the
          // state reads below are consumed.
          const float emt = fb[(t & 31) * 64 + gj];
          const v4f A0 = sv[0], A1 = sv[1], A2 = sv[2], A3 = sv[3],
                    A4 = sv[4];
          const float A5 = sb[20];

          float d0 = A0[0] * ec[0], d1 = A0[1] * ec[1], d2 = A0[2] * ec[2];
          d0 = fmaf(A0[3], ec[3], d0); d1 = fmaf(A1[0], ec[4], d1);
          d2 = fmaf(A1[1], ec[5], d2);
          d0 = fmaf(A1[2], ec[6], d0); d1 = fmaf(A1[3], ec[7], d1);
          d2 = fmaf(A2[0], ec[8], d2);
          d0 = fmaf(A2[1], ec[9], d0); d1 = fmaf(A2[2], ec[10], d1);
          d2 = fmaf(A2[3], ec[11], d2);
          d0 = fmaf(A3[0], ec[12], d0); d1 = fmaf(A3[1], ec[13], d1);
          d2 = fmaf(A3[2], ec[14], d2);
          d0 = fmaf(A3[3], ec[15], d0); d1 = fmaf(A4[0], ec[16], d1);
          d2 = fmaf(A4[1], ec[17], d2);
          d0 = fmaf(A4[2], ec[18], d0); d1 = fmaf(A4[3], ec[19], d1);
          d2 = fmaf(A5, ec[20], d2);

          const float pn = ((d0 + d1) + d2) * __expf(emt);
          p = (t < mylen) ? pn : p;
          if ((t & 7) == 0) {
            // group-uniform renorm by OLD p[0] (in registers)
            const float f = A0[0];
            p *= __builtin_amdgcn_rcpf(f);
            L += __logf(f);
          }
          sb[jloc] = p;  // state for step t+1
        }
        if (c < 7) {
          WAIT_VM0()                 // stage(c+1) landed long ago: free
          if (c + 2 < 8) STAGE(c + 2)
        }
      }

      const float w = p * __expf(endT[jloc]);
      float res = 0.f;
#pragma unroll
      for (int gg = 0; gg < 3; ++gg) {
        if (b0 + gg < B_) {
          float tot = 0.f;
#pragma unroll
          for (int i = 0; i < K_; ++i) tot += rdl(w, gg * K_ + i);
          res += rdl(L, gg * K_) + __logf(tot);
        }
      }
      if (lane == 0) atomicAdd(out_loss, res);  // +den
    } else {
      // ---------------- Viterbi ----------------
      float tr[21];  // trans[:, jloc] + 2048 straight (no rotation)
#pragma unroll
      for (int i = 0; i < K_; ++i) tr[i] = trans[i * K_ + jloc] + 2048.0f;
      float sc = startT[jloc] + em0;
      sb[jloc] = sc;

      for (int c = 0; c < 8; ++c) {
        const float* fb = &fcs[c & 1][0][0];
        const int t1 = c * 32 + 32;
        for (int t = c ? c * 32 : 1; t < t1; ++t) {
          const float emt = fb[(t & 31) * 64 + gj];
          const v4f A0 = sv[0], A1 = sv[1], A2 = sv[2], A3 = sv[3],
                    A4 = sv[4];
          const float A5 = sb[20];

          // key = (bits & ~31) | (20-i): larger key <=> smaller prev tag
          // (first-argmax). All keys positive (score+2048 > 0).
#define KEY(i, V) ((__float_as_int((V) + tr[i]) & 0xFFFFFFE0) | (20 - (i)))
          const int q0 = imax3(KEY(0, A0[0]), KEY(1, A0[1]), KEY(2, A0[2]));
          const int q1 = imax3(KEY(3, A0[3]), KEY(4, A1[0]), KEY(5, A1[1]));
          const int q2 = imax3(KEY(6, A1[2]), KEY(7, A1[3]), KEY(8, A2[0]));
          const int q3 = imax3(KEY(9, A2[1]), KEY(10, A2[2]), KEY(11, A2[3]));
          const int q4 = imax3(KEY(12, A3[0]), KEY(13, A3[1]), KEY(14, A3[2]));
          const int q5 = imax3(KEY(15, A3[3]), KEY(16, A4[0]), KEY(17, A4[1]));
          const int q6 = imax3(KEY(18, A4[2]), KEY(19, A4[3]), KEY(20, A5));
          const int km = imax3(imax3(q0, q1, q2), imax3(q3, q4, q5), q6);
#undef KEY
          const float nxt = __int_as_float(km & 0xFFFFFFE0) - 2048.0f + emt;
          const bool m = t < mylen;
          sc = m ? nxt : sc;
          sb[jloc] = sc;  // state for step t+1
          const int pw = m ? (20 - (km & 31)) : jloc;  // identity when frozen
          // unguarded: lane 63 writes the same value as lane 62 (same gj)
          bp[t * 66 + g * 22 + jloc] = (unsigned short)pw;
        }
        if (c < 7) {
          WAIT_VM0()
          if (c + 2 < 8) STAGE(c + 2)
        }
      }
      __syncthreads();

      // final argmax per group (tie-break: smallest tag)
      const float finb = sc + endT[jloc] + 2048.0f;
      const int myk = (__float_as_int(finb) & 0xFFFFFFE0) | (20 - jloc);
      int last0 = 0, last1 = 0, last2 = 0;
#pragma unroll
      for (int gg = 0; gg < 3; ++gg) {
        int km = 0;
#pragma unroll
        for (int i = 0; i < K_; ++i) {
          const int ki = __builtin_amdgcn_readlane(myk, gg * K_ + i);
          km = km > ki ? km : ki;
        }
        const int lt = 20 - (km & 31);
        if (gg == 0) last0 = lt;
        else if (gg == 1) last1 = lt;
        else last2 = lt;
      }

      // skip tables (parallel over lanes)
      for (int i = lane; i < 127 * 63; i += 64) {
        const int v = i / 63;
        const int rem = i - v * 63;
        const int gg = rem / 21, j = rem - (rem / 21) * 21;
        h2[v * 66 + gg * 22 + j] = (unsigned char)
            bp[(2 * v + 1) * 66 + gg * 22 + bp[(2 * v + 2) * 66 + gg * 22 + j]];
      }
      __syncthreads();
      for (int i = lane; i < 63 * 63; i += 64) {
        const int w = i / 63;
        const int rem = i - w * 63;
        const int gg = rem / 21, j = rem - (rem / 21) * 21;
        h4[w * 66 + gg * 22 + j] =
            h2[(2 * w) * 66 + gg * 22 + h2[(2 * w + 1) * 66 + gg * 22 + j]];
      }
      __syncthreads();

      // 3 parallel serial chases (lane == group)
      if (lane < 3 && b0 + lane < B_) {
        int c = (lane == 0) ? last0 : (lane == 1) ? last1 : last2;
        cur[lane * 256 + 255] = (unsigned char)c;
        c = bp[255 * 66 + lane * 22 + c];
        cur[lane * 256 + 254] = (unsigned char)c;
        c = h2[126 * 66 + lane * 22 + c];
        cur[lane * 256 + 252] = (unsigned char)c;
        for (int w = 62; w >= 0; --w) {
          c = h4[w * 66 + lane * 22 + c];
          cur[lane * 256 + 4 * w] = (unsigned char)c;
        }
      }
      __syncthreads();
      for (int i = lane; i < 63 * 3; i += 64) {  // t = 2 mod 4
        const int gg = i / 63, ii = i - (i / 63) * 63;
        const int t = 2 + 4 * ii;
        cur[gg * 256 + t] =
            h2[(t >> 1) * 66 + gg * 22 + cur[gg * 256 + t + 2]];
      }
      __syncthreads();
      for (int i = lane; i < 127 * 3; i += 64) {  // odd t
        const int gg = i / 127, ii = i - (i / 127) * 127;
        const int t = 1 + 2 * ii;
        cur[gg * 256 + t] = (unsigned char)
            bp[(t + 1) * 66 + gg * 22 + cur[gg * 256 + t + 1]];
      }
      __syncthreads();
      for (int i = lane; i < 3 * 256; i += 64) {
        const int gg = i >> 8, t = i & 255;
        const int bb = b0 + gg;
        const int lg = (gg == 0) ? len0 : (gg == 1) ? len1 : len2;
        if (bb < B_)
          out_tags[t * B_ + bb] = (t < lg) ? (float)cur[gg * 256 + t] : 0.f;
      }
    }
#undef STAGE
#undef WAIT_VM0
  } else {
    // ---------------- numerator ----------------
    const int b = blk - 2 * NB3;
    float contrib = 0.f;
#pragma unroll
    for (int q = 0; q < 4; ++q) {
      const int t = lane * 4 + q;
      const int tg = tags[t * B_ + b];
      const size_t ro = ((size_t)t * B_ + b) * K_;
      if (t == 0) {
        contrib += startT[tg] + fc[ro + tg];
      } else if (tg != 0) {
        const int pg = tags[(t - 1) * B_ + b];
        contrib += trans[pg * K_ + tg] + fc[ro + tg];
      }
      const bool isLast =
          (tg != 0) && (t == T_ - 1 || tags[(t + 1) * B_ + b] == 0);
      if (isLast) contrib += endT[tg];
    }
#pragma unroll
    for (int off = 32; off > 0; off >>= 1)
      contrib += __shfl_down(contrib, off, 64);
    if (lane == 0) atomicAdd(out_loss, -contrib);  // -num
  }
}

extern "C" void kernel_launch(void* const* d_in, const int* in_sizes, int n_in,
                              void* d_out, int out_size, void* d_ws,
                              size_t ws_size, hipStream_t stream) {
  const float* A = (const float*)d_in[0];
  const int* tags = (const int*)d_in[1];
  const float* W = (const float*)d_in[2];
  const float* bias = (const float*)d_in[3];
  const float* startT = (const float*)d_in[4];
  const float* endT = (const float*)d_in[5];
  const float* trans = (const float*)d_in[6];

  float* out_tags = (float*)d_out;
  float* out_loss = (float*)d_out + (size_t)T_ * B_;
  float* fc = (float*)d_ws;  // [t*B+b][21] f32, 2.75 MB

  fc_kernel<<<512, 256, 0, stream>>>(A, W, bias, fc, out_loss);
  scan_kernel<<<2 * NB3 + B_, 64, 0, stream>>>(fc, tags, startT, endT, trans,
                                               out_tags, out_loss);
}